// Round 17
// baseline (50.915 us; speedup 1.0000x reference)
//
#include <hip/hip_runtime.h>
#include <hip/hip_bf16.h>

typedef __bf16 bf16_t;
typedef __bf16 bf16x4 __attribute__((ext_vector_type(4)));
typedef __bf16 bf16x8 __attribute__((ext_vector_type(8)));
typedef float f32x4 __attribute__((ext_vector_type(4)));
typedef float f32x16 __attribute__((ext_vector_type(16)));
typedef long i64x2 __attribute__((ext_vector_type(2)));
typedef int i32x4 __attribute__((ext_vector_type(4)));

#define BATCH 128
#define NS 512
#define DIM 256
#define NTB 20       // 128x64 tiles per batch (tjc >= 2*ti)
#define LDSP 272     // bytes per 256-fp8 row (16B-aligned pad; measured 0 bank conflicts)

__device__ __forceinline__ void decode_tile(int r20, int& ti, int& tjc) {
    if (r20 < 8)       { ti = 0; tjc = r20; }
    else if (r20 < 14) { ti = 1; tjc = r20 - 6; }
    else if (r20 < 18) { ti = 2; tjc = r20 - 10; }
    else               { ti = 3; tjc = r20 - 12; }
}

// ===== Kernel A: {S^T + denom} U {dv -> fp8 + norms} U {S permute into C/D order} =====
__global__ __launch_bounds__(256) void prep_st_kernel(const float* __restrict__ dv,
                                                      const float* __restrict__ S,
                                                      unsigned char* __restrict__ f8,
                                                      float* __restrict__ n2g,
                                                      float* __restrict__ St,
                                                      float* __restrict__ dpartial,
                                                      float* __restrict__ Sp1,
                                                      float* __restrict__ Sp2) {
    const int bidx = blockIdx.x;
    const int t = threadIdx.x;
    if (bidx < 256) {
        const int bi = bidx >> 4, bj = bidx & 15;
        const int c  = t & 31, r0 = t >> 5;
        __shared__ float tileS[32][33];
        __shared__ float red[4];
        float dacc = 0.0f;
#pragma unroll
        for (int k = 0; k < 4; ++k) {
            const int r  = r0 + k * 8;
            const int gi = bi * 32 + r, gj = bj * 32 + c;
            const float s = S[(size_t)gi * NS + gj];
            tileS[r][c] = s;
            const float w = (s > 0.0f) ? 1.0f : 0.0f;
            const float e = (gi == gj) ? 1.0f : 0.0f;
            const float d = w - e;
            dacc += d * d;
        }
        __syncthreads();
#pragma unroll
        for (int k = 0; k < 4; ++k) {
            const int r = r0 + k * 8;
            St[(size_t)(bj * 32 + r) * NS + bi * 32 + c] = tileS[c][r];
        }
        const int lane = t & 63, wave = t >> 6;
#pragma unroll
        for (int off = 32; off >= 1; off >>= 1) dacc += __shfl_down(dacc, off, 64);
        if (lane == 0) red[wave] = dacc;
        __syncthreads();
        if (t == 0) dpartial[bidx] = red[0] + red[1] + red[2] + red[3];
    } else if (bidx < 2304) {
        const int wid  = ((bidx - 256) << 2) | (t >> 6);   // 0..8191
        const int lane = t & 63;
#pragma unroll
        for (int it = 0; it < 8; ++it) {
            const int row = wid + it * 8192;               // 65536 rows total
            const f32x4 v = *reinterpret_cast<const f32x4*>(dv + (size_t)row * DIM + lane * 4);
            float pn = v[0]*v[0] + v[1]*v[1] + v[2]*v[2] + v[3]*v[3];
#pragma unroll
            for (int off = 32; off >= 1; off >>= 1) pn += __shfl_xor(pn, off, 64);
            int w0 = __builtin_amdgcn_cvt_pk_fp8_f32(v[0], v[1], 0, false);
            w0     = __builtin_amdgcn_cvt_pk_fp8_f32(v[2], v[3], w0, true);
            *reinterpret_cast<int*>(f8 + (size_t)row * DIM + lane * 4) = w0;
            if (lane == 0) n2g[row] = pn;
        }
    } else {
        // ---- permute S into per-(tile,wave,lane) C/D fragment order ----
        const int bid2 = bidx - 2304;    // 0..159 = (r20, wave)
        const int r20 = bid2 >> 3, w = bid2 & 7;
        int ti, tjc;
        decode_tile(r20, ti, tjc);
        const bool single = ((tjc >> 1) == ti);
        const int l = t >> 2, h4 = t & 3;        // 64 lanes x 4 h4-groups
        const int wr = w >> 1, wc = w & 1;
        const int col = l & 31, kh = l >> 5;
        const int lj  = wc * 32 + col;
        const int gj  = tjc * 64 + lj;
        const int li0 = wr * 32 + h4 * 8 + kh * 4;
        const int gi0 = ti * 128 + li0;
        const size_t base = ((size_t)(r20 * 8 + w) * 64 + l) * 16 + h4 * 4;
        f32x4 s1v;
#pragma unroll
        for (int e = 0; e < 4; ++e) s1v[e] = S[(size_t)(gi0 + e) * NS + gj];
        f32x4 s2v = (f32x4)(0.0f);
        if (!single) s2v = *reinterpret_cast<const f32x4*>(S + (size_t)gj * NS + gi0);
        *reinterpret_cast<f32x4*>(Sp1 + base) = s1v;
        *reinterpret_cast<f32x4*>(Sp2 + base) = s2v;
    }
}

// ===== Kernel C: fp8 128x64-tile gram, 2 barriers, direct C/D epilogue via Sp1/Sp2 =====
// grid 2560 x 512 threads (8 waves, 4x2; wave owns 32x32). Block = (batch, (ti,tjc)).
__global__ __launch_bounds__(512, 6) void gram_pair_kernel(const unsigned char* __restrict__ f8,
                                                           const float* __restrict__ n2g,
                                                           const float* __restrict__ Sp1,
                                                           const float* __restrict__ Sp2,
                                                           float* __restrict__ partial) {
    const int bid  = blockIdx.x;
    const int work = (bid & 7) * 320 + (bid >> 3);   // bijective; XCD x owns batches [x*16,(x+1)*16)
    const int b    = work / NTB;
    const int r20  = work - b * NTB;
    int ti, tjc;
    decode_tile(r20, ti, tjc);
    const bool single = ((tjc >> 1) == ti);          // straddles the diagonal 128x128 block
    const int t    = threadIdx.x;
    const int wave = t >> 6, lane = t & 63;
    const int wr   = wave >> 1, wc = wave & 1;       // 4x2 wave grid; wave owns 32x32
    const int col  = lane & 31, kh = lane >> 5;

    __shared__ __attribute__((aligned(16))) char sP[192 * LDSP];  // A[128]+B[64] fp8 panels
    __shared__ float n2s[192];
    __shared__ float red[8];

    // ---- staging: contiguous fp8 panels; 16 threads/row, dense 8KB per wave-instr ----
    {
        const unsigned char* srcA = f8 + ((size_t)b * NS + (size_t)ti * 128) * DIM;
#pragma unroll
        for (int it = 0; it < 4; ++it) {
            const i32x4 v = *reinterpret_cast<const i32x4*>(srcA + it * 8192 + t * 16);
            *reinterpret_cast<i32x4*>(&sP[(it * 32 + (t >> 4)) * LDSP + (t & 15) * 16]) = v;
        }
        const unsigned char* srcB = f8 + ((size_t)b * NS + (size_t)tjc * 64) * DIM;
#pragma unroll
        for (int it = 0; it < 2; ++it) {
            const i32x4 v = *reinterpret_cast<const i32x4*>(srcB + it * 8192 + t * 16);
            *reinterpret_cast<i32x4*>(&sP[(128 + it * 32 + (t >> 4)) * LDSP + (t & 15) * 16]) = v;
        }
        if (t < 128)      n2s[t] = n2g[(size_t)b * NS + (size_t)ti * 128 + t];
        else if (t < 192) n2s[t] = n2g[(size_t)b * NS + (size_t)tjc * 64 + (t - 128)];
    }
    __syncthreads();

    // ---- MFMA: 8 u x (2 ds_read_b128 + 2 mfma_32x32x16_fp8) ----
    const char* aP = &sP[(wr * 32 + col) * LDSP + kh * 16];
    const char* bP = &sP[(128 + wc * 32 + col) * LDSP + kh * 16];
    f32x16 acc = (f32x16)(0.0f);
    __builtin_amdgcn_s_setprio(1);
#pragma unroll
    for (int u = 0; u < 8; ++u) {
        // identical k-gather on A and B -> any k-permutation cancels in A.A^T
        const i64x2 Av = *reinterpret_cast<const i64x2*>(aP + u * 32);
        const i64x2 Bv = *reinterpret_cast<const i64x2*>(bP + u * 32);
        acc = __builtin_amdgcn_mfma_f32_32x32x16_fp8_fp8(Av[0], Bv[0], acc, 0, 0, 0);
        acc = __builtin_amdgcn_mfma_f32_32x32x16_fp8_fp8(Av[1], Bv[1], acc, 0, 0, 0);
    }
    __builtin_amdgcn_s_setprio(0);

    // ---- epilogue in C/D order; S/St from permuted buffers (contiguous per thread) ----
    // C/D 32x32 layout: col=lane&31, row=(reg&3)+8*(reg>>2)+4*(lane>>5)
    float local = 0.0f;
    {
        const int lj = wc * 32 + col;
        const int gj = tjc * 64 + lj;
        const float n2j = n2s[128 + lj];
        const float* sp1 = Sp1 + ((size_t)(r20 * 8 + wave) * 64 + lane) * 16;
        const float* sp2 = Sp2 + ((size_t)(r20 * 8 + wave) * 64 + lane) * 16;
#pragma unroll
        for (int h4 = 0; h4 < 4; ++h4) {
            const f32x4 s1v = *reinterpret_cast<const f32x4*>(sp1 + h4 * 4);
            const f32x4 s2v = *reinterpret_cast<const f32x4*>(sp2 + h4 * 4);
#pragma unroll
            for (int e = 0; e < 4; ++e) {
                const int li = wr * 32 + h4 * 8 + kh * 4 + e;
                const float c = acc[h4 * 4 + e];
                const float sq = fmaxf(n2s[li] + n2j - 2.0f * c, 0.0f);
                const float dist = __builtin_amdgcn_sqrtf(sq);
                const float kd = __expf(-dist);
                const float s1 = s1v[e];
                if (single) {
                    const int gi = ti * 128 + li;
                    float d = (gi == gj) ? (1.0f - s1) : (kd - s1);
                    d *= (s1 > 0.0f) ? 1.0f : 0.0f;
                    local += d * d;
                } else {
                    const float s2 = s2v[e];
                    const float d1 = (s1 > 0.0f) ? (kd - s1) : 0.0f;
                    const float d2 = (s2 > 0.0f) ? (kd - s2) : 0.0f;
                    local += d1 * d1 + d2 * d2;
                }
            }
        }
    }

#pragma unroll
    for (int off = 32; off >= 1; off >>= 1) local += __shfl_down(local, off, 64);
    if (lane == 0) red[wave] = local;
    __syncthreads();
    if (t == 0) {
        float s = 0.0f;
#pragma unroll
        for (int w = 0; w < 8; ++w) s += red[w];
        partial[(size_t)b * NTB + r20] = s;
    }
}

// =================== fallback path (R2, known-good; used if ws too small) ===================

__global__ __launch_bounds__(256) void norms_kernel(const float* __restrict__ dv,
                                                    float* __restrict__ n2) {
    const int row  = blockIdx.x * 4 + (threadIdx.x >> 6);
    const int lane = threadIdx.x & 63;
    const float4 v = *reinterpret_cast<const float4*>(dv + (size_t)row * DIM + lane * 4);
    float s = v.x * v.x + v.y * v.y + v.z * v.z + v.w * v.w;
#pragma unroll
    for (int off = 32; off >= 1; off >>= 1) s += __shfl_down(s, off, 64);
    if (lane == 0) n2[row] = s;
}

__global__ __launch_bounds__(256) void denom_kernel(const float* __restrict__ Smat,
                                                    float* __restrict__ dpartial) {
    const int t = threadIdx.x;
    const int lane = t & 63, wave = t >> 6;
    __shared__ float sred[4];
    float acc = 0.0f;
    const int base = blockIdx.x * 512;
#pragma unroll
    for (int r = 0; r < 2; ++r) {
        const int v4 = base + r * 256 + t;
        const float4 s4 = reinterpret_cast<const float4*>(Smat)[v4];
        const int idx0 = v4 * 4;
        const int i = idx0 >> 9;
#pragma unroll
        for (int c = 0; c < 4; ++c) {
            const float s = (&s4.x)[c];
            const int j = (idx0 + c) & (NS - 1);
            const float w = (s > 0.0f) ? 1.0f : 0.0f;
            const float e = (i == j) ? 1.0f : 0.0f;
            const float d = w - e;
            acc += d * d;
        }
    }
#pragma unroll
    for (int off = 32; off >= 1; off >>= 1) acc += __shfl_down(acc, off, 64);
    if (lane == 0) sred[wave] = acc;
    __syncthreads();
    if (t == 0) dpartial[blockIdx.x] = sred[0] + sred[1] + sred[2] + sred[3];
}

#define FLDSK 40
__global__ __launch_bounds__(256) void gram_f32_kernel(const float* __restrict__ dv,
                                                       const float* __restrict__ Smat,
                                                       const float* __restrict__ n2,
                                                       float* __restrict__ partial) {
    const int tile = blockIdx.x;
    const int b    = blockIdx.y;
    const int ti   = tile >> 2, tj = tile & 3;
    const int t    = threadIdx.x;
    const int wave = t >> 6, lane = t & 63;
    const int wr   = wave >> 1, wc = wave & 1;

    __shared__ bf16_t sA[128 * FLDSK];
    __shared__ bf16_t sB[128 * FLDSK];
    __shared__ float red[4];

    const float* Abase = dv + ((size_t)b * NS + (size_t)ti * 128) * DIM;
    const float* Bbase = dv + ((size_t)b * NS + (size_t)tj * 128) * DIM;

    f32x4 acc[4][4];
#pragma unroll
    for (int m = 0; m < 4; ++m)
#pragma unroll
        for (int n = 0; n < 4; ++n) acc[m][n] = (f32x4)(0.0f);

    const int fr = lane & 15;
    const int g  = lane >> 4;

    for (int ks = 0; ks < DIM; ks += 32) {
        float4 ra[4], rb[4];
#pragma unroll
        for (int i = 0; i < 4; ++i) {
            const int c   = i * 256 + t;
            const int row = c >> 3;
            const int kc  = (c & 7) * 4;
            ra[i] = *reinterpret_cast<const float4*>(Abase + (size_t)row * DIM + ks + kc);
            rb[i] = *reinterpret_cast<const float4*>(Bbase + (size_t)row * DIM + ks + kc);
        }
        __syncthreads();
#pragma unroll
        for (int i = 0; i < 4; ++i) {
            const int c   = i * 256 + t;
            const int row = c >> 3;
            const int kc  = (c & 7) * 4;
            bf16x4 va = { (bf16_t)ra[i].x, (bf16_t)ra[i].y, (bf16_t)ra[i].z, (bf16_t)ra[i].w };
            bf16x4 vb = { (bf16_t)rb[i].x, (bf16_t)rb[i].y, (bf16_t)rb[i].z, (bf16_t)rb[i].w };
            *reinterpret_cast<bf16x4*>(&sA[row * FLDSK + kc]) = va;
            *reinterpret_cast<bf16x4*>(&sB[row * FLDSK + kc]) = vb;
        }
        __syncthreads();

        bf16x8 afrag[4], bfrag[4];
#pragma unroll
        for (int m = 0; m < 4; ++m)
            afrag[m] = *reinterpret_cast<const bf16x8*>(&sA[(wr * 64 + m * 16 + fr) * FLDSK + g * 8]);
#pragma unroll
        for (int n = 0; n < 4; ++n)
            bfrag[n] = *reinterpret_cast<const bf16x8*>(&sB[(wc * 64 + n * 16 + fr) * FLDSK + g * 8]);
#pragma unroll
        for (int m = 0; m < 4; ++m)
#pragma unroll
            for (int n = 0; n < 4; ++n)
                acc[m][n] = __builtin_amdgcn_mfma_f32_16x16x32_bf16(afrag[m], bfrag[n], acc[m][n], 0, 0, 0);
    }

    float local = 0.0f;
    const float* n2b = n2 + (size_t)b * NS;
    const int rowbase = ti * 128 + wr * 64;
    const int colbase = tj * 128 + wc * 64;
#pragma unroll
    for (int m = 0; m < 4; ++m) {
#pragma unroll
        for (int n = 0; n < 4; ++n) {
            const int gi0 = rowbase + m * 16 + g * 4;
            const int gj  = colbase + n * 16 + fr;
            const float ncol = n2b[gj];
#pragma unroll
            for (int j = 0; j < 4; ++j) {
                const int gi = gi0 + j;
                const float cij = acc[m][n][j];
                float sq = fmaxf(n2b[gi] + ncol - 2.0f * cij, 0.0f);
                const float dist = sqrtf(sq);
                const float kd = __expf(-dist);
                const float s = Smat[(size_t)gi * NS + gj];
                const float w = (s > 0.0f) ? 1.0f : 0.0f;
                float d = (gi == gj) ? (1.0f - s) : (kd - s);
                d *= w;
                local += d * d;
            }
        }
    }
#pragma unroll
    for (int off = 32; off >= 1; off >>= 1) local += __shfl_down(local, off, 64);
    if (lane == 0) red[wave] = local;
    __syncthreads();
    if (t == 0) partial[(size_t)b * 16 + tile] = red[0] + red[1] + red[2] + red[3];
}

// =================== shared finalize ===================
__global__ __launch_bounds__(256) void finalize_kernel(const float* __restrict__ dpartial, int ndp,
                                                       const float* __restrict__ partial, int ntiles,
                                                       float* __restrict__ out) {
    const int t = threadIdx.x;
    const int lane = t & 63, wave = t >> 6;
    __shared__ float sred[4];
    __shared__ float sred2[4];

    float dacc = (t < ndp) ? dpartial[t] : 0.0f;
#pragma unroll
    for (int off = 32; off >= 1; off >>= 1) dacc += __shfl_down(dacc, off, 64);
    if (lane == 0) sred[wave] = dacc;
    __syncthreads();
    const float denom = sqrtf(sred[0] + sred[1] + sred[2] + sred[3]);

    float lsum = 0.0f;
    if (t < BATCH) {
        float ss = 0.0f;
        for (int k = 0; k < ntiles; ++k) ss += partial[(size_t)t * ntiles + k];
        lsum = 2.0f * sqrtf(ss) / denom;
    }
#pragma unroll
    for (int off = 32; off >= 1; off >>= 1) lsum += __shfl_down(lsum, off, 64);
    if (lane == 0) sred2[wave] = lsum;
    __syncthreads();
    if (t == 0) out[0] = sred2[0] + sred2[1] + sred2[2] + sred2[3];
}

extern "C" void kernel_launch(void* const* d_in, const int* in_sizes, int n_in,
                              void* d_out, int out_size, void* d_ws, size_t ws_size,
                              hipStream_t stream) {
    const float* dv   = (const float*)d_in[0];   // [128,512,256] fp32
    const float* Smat = (const float*)d_in[1];   // [512,512] fp32
    float* out = (float*)d_out;

    const size_t f8_bytes = (size_t)BATCH * NS * DIM;     // 16 MB
    const size_t st_bytes = (size_t)NS * NS * 4;          // 1 MB
    const size_t n2_bytes = (size_t)BATCH * NS * 4;       // 256 KB
    const size_t sp_bytes = (size_t)NTB * 8 * 64 * 16 * 4; // 655 KB each
    const size_t pt_bytes = (size_t)BATCH * NTB * 4;      // 10 KB
    const size_t dp_bytes = 256 * 4;
    const size_t need = f8_bytes + st_bytes + n2_bytes + 2 * sp_bytes + pt_bytes + dp_bytes;

    if (ws_size >= need) {
        char* w = (char*)d_ws;
        unsigned char* f8 = (unsigned char*)w;  w += f8_bytes;
        float* St      = (float*)w;   w += st_bytes;
        float* n2g     = (float*)w;   w += n2_bytes;
        float* Sp1     = (float*)w;   w += sp_bytes;
        float* Sp2     = (float*)w;   w += sp_bytes;
        float* partial = (float*)w;   w += pt_bytes;
        float* dpart   = (float*)w;

        prep_st_kernel<<<dim3(2464), 256, 0, stream>>>(dv, Smat, f8, n2g, St, dpart, Sp1, Sp2);
        gram_pair_kernel<<<dim3(NTB * BATCH), 512, 0, stream>>>(f8, n2g, Sp1, Sp2, partial);
        finalize_kernel<<<dim3(1), 256, 0, stream>>>(dpart, 256, partial, NTB, out);
    } else {
        float* n2      = (float*)d_ws;
        float* partial = n2 + (size_t)BATCH * NS;
        float* dpart   = partial + (size_t)BATCH * 16;

        norms_kernel<<<dim3(BATCH * NS / 4), 256, 0, stream>>>(dv, n2);
        denom_kernel<<<dim3(128), 256, 0, stream>>>(Smat, dpart);
        gram_f32_kernel<<<dim3(16, BATCH), 256, 0, stream>>>(dv, Smat, n2, partial);
        finalize_kernel<<<dim3(1), 256, 0, stream>>>(dpart, 128, partial, 16, out);
    }
}

// Round 18
// 44.370 us; speedup vs baseline: 1.1475x; 1.1475x over previous
//
#include <hip/hip_runtime.h>
#include <hip/hip_bf16.h>

typedef __bf16 bf16_t;
typedef __bf16 bf16x4 __attribute__((ext_vector_type(4)));
typedef __bf16 bf16x8 __attribute__((ext_vector_type(8)));
typedef float f32x4 __attribute__((ext_vector_type(4)));
typedef float f32x16 __attribute__((ext_vector_type(16)));
typedef long i64x2 __attribute__((ext_vector_type(2)));
typedef int i32x4 __attribute__((ext_vector_type(4)));

#define BATCH 128
#define NS 512
#define DIM 256
#define NTB 20       // 128x64 tiles per batch (tjc >= 2*ti)
#define LDSP 272     // bytes per 256-fp8 row (16B-aligned pad; measured 0 bank conflicts)
#define CST 68       // f32 words per sC row (64 cols + pad)

// ============ Kernel A: fused {S^T + denom partials} U {dv -> fp8 + row norms} ============
__global__ __launch_bounds__(256) void prep_st_kernel(const float* __restrict__ dv,
                                                      const float* __restrict__ S,
                                                      unsigned char* __restrict__ f8,
                                                      float* __restrict__ n2g,
                                                      float* __restrict__ St,
                                                      float* __restrict__ dpartial) {
    const int bidx = blockIdx.x;
    const int t = threadIdx.x;
    if (bidx < 256) {
        const int bi = bidx >> 4, bj = bidx & 15;
        const int c  = t & 31, r0 = t >> 5;
        __shared__ float tileS[32][33];
        __shared__ float red[4];
        float dacc = 0.0f;
#pragma unroll
        for (int k = 0; k < 4; ++k) {
            const int r  = r0 + k * 8;
            const int gi = bi * 32 + r, gj = bj * 32 + c;
            const float s = S[(size_t)gi * NS + gj];
            tileS[r][c] = s;
            const float w = (s > 0.0f) ? 1.0f : 0.0f;
            const float e = (gi == gj) ? 1.0f : 0.0f;
            const float d = w - e;
            dacc += d * d;
        }
        __syncthreads();
#pragma unroll
        for (int k = 0; k < 4; ++k) {
            const int r = r0 + k * 8;
            St[(size_t)(bj * 32 + r) * NS + bi * 32 + c] = tileS[c][r];
        }
        const int lane = t & 63, wave = t >> 6;
#pragma unroll
        for (int off = 32; off >= 1; off >>= 1) dacc += __shfl_down(dacc, off, 64);
        if (lane == 0) red[wave] = dacc;
        __syncthreads();
        if (t == 0) dpartial[bidx] = red[0] + red[1] + red[2] + red[3];
    } else {
        const int wid  = ((bidx - 256) << 2) | (t >> 6);   // 0..8191
        const int lane = t & 63;
#pragma unroll
        for (int it = 0; it < 8; ++it) {
            const int row = wid + it * 8192;               // 65536 rows total
            const f32x4 v = *reinterpret_cast<const f32x4*>(dv + (size_t)row * DIM + lane * 4);
            float pn = v[0]*v[0] + v[1]*v[1] + v[2]*v[2] + v[3]*v[3];
#pragma unroll
            for (int off = 32; off >= 1; off >>= 1) pn += __shfl_xor(pn, off, 64);
            int w0 = __builtin_amdgcn_cvt_pk_fp8_f32(v[0], v[1], 0, false);
            w0     = __builtin_amdgcn_cvt_pk_fp8_f32(v[2], v[3], w0, true);
            *reinterpret_cast<int*>(f8 + (size_t)row * DIM + lane * 4) = w0;
            if (lane == 0) n2g[row] = pn;
        }
    }
}

// ============ Kernel C: fp8 128x64-tile gram, 3 blocks/CU, LDS-C epilogue (R12 exact) ============
// grid 2560 x 512 threads (8 waves, 4x2; wave owns 32x32). Block = (batch, (ti,tjc)).
// Tiles with tjc in {2ti, 2ti+1} are single-count (straddle diagonal block); others mirror.
__global__ __launch_bounds__(512, 6) void gram_pair_kernel(const unsigned char* __restrict__ f8,
                                                           const float* __restrict__ n2g,
                                                           const float* __restrict__ S,
                                                           const float* __restrict__ St,
                                                           float* __restrict__ partial) {
    const int bid  = blockIdx.x;
    const int work = (bid & 7) * 320 + (bid >> 3);   // bijective; XCD x owns batches [x*16,(x+1)*16)
    const int b    = work / NTB;
    const int r20  = work - b * NTB;
    int ti, tjc;
    if (r20 < 8)       { ti = 0; tjc = r20; }
    else if (r20 < 14) { ti = 1; tjc = r20 - 6; }
    else if (r20 < 18) { ti = 2; tjc = r20 - 10; }
    else               { ti = 3; tjc = r20 - 12; }
    const bool single = ((tjc >> 1) == ti);          // straddles the diagonal 128x128 block
    const int t    = threadIdx.x;
    const int wave = t >> 6, lane = t & 63;
    const int wr   = wave >> 1, wc = wave & 1;       // 4x2 wave grid; wave owns 32x32
    const int col  = lane & 31, kh = lane >> 5;

    __shared__ __attribute__((aligned(16))) char smem[192 * LDSP];  // A[128]+B[64]; reused as sC f32[128][68]
    __shared__ float n2s[192];
    __shared__ float red[8];
    char*  sP = smem;
    float* sC = reinterpret_cast<float*>(smem);

    // ---- staging: contiguous fp8 panels; 16 threads/row, dense 8KB per wave-instr ----
    {
        const unsigned char* srcA = f8 + ((size_t)b * NS + (size_t)ti * 128) * DIM;
#pragma unroll
        for (int it = 0; it < 4; ++it) {
            const i32x4 v = *reinterpret_cast<const i32x4*>(srcA + it * 8192 + t * 16);
            *reinterpret_cast<i32x4*>(&sP[(it * 32 + (t >> 4)) * LDSP + (t & 15) * 16]) = v;
        }
        const unsigned char* srcB = f8 + ((size_t)b * NS + (size_t)tjc * 64) * DIM;
#pragma unroll
        for (int it = 0; it < 2; ++it) {
            const i32x4 v = *reinterpret_cast<const i32x4*>(srcB + it * 8192 + t * 16);
            *reinterpret_cast<i32x4*>(&sP[(128 + it * 32 + (t >> 4)) * LDSP + (t & 15) * 16]) = v;
        }
        if (t < 128)      n2s[t] = n2g[(size_t)b * NS + (size_t)ti * 128 + t];
        else if (t < 192) n2s[t] = n2g[(size_t)b * NS + (size_t)tjc * 64 + (t - 128)];
    }
    __syncthreads();

    // ---- MFMA: 8 u x (2 ds_read_b128 + 2 mfma_32x32x16_fp8) ----
    const char* aP = &sP[(wr * 32 + col) * LDSP + kh * 16];
    const char* bP = &sP[(128 + wc * 32 + col) * LDSP + kh * 16];
    f32x16 acc = (f32x16)(0.0f);
    __builtin_amdgcn_s_setprio(1);
#pragma unroll
    for (int u = 0; u < 8; ++u) {
        // identical k-gather on A and B -> any k-permutation cancels in A.A^T
        const i64x2 Av = *reinterpret_cast<const i64x2*>(aP + u * 32);
        const i64x2 Bv = *reinterpret_cast<const i64x2*>(bP + u * 32);
        acc = __builtin_amdgcn_mfma_f32_32x32x16_fp8_fp8(Av[0], Bv[0], acc, 0, 0, 0);
        acc = __builtin_amdgcn_mfma_f32_32x32x16_fp8_fp8(Av[1], Bv[1], acc, 0, 0, 0);
    }
    __builtin_amdgcn_s_setprio(0);
    __syncthreads();   // all waves done reading panels; smem reused as sC

    // ---- writer: kd = exp(-dist) into sC. C/D 32x32 layout col=lane&31, row=(reg&3)+8*(reg>>2)+4*(lane>>5)
    {
        const int lj = wc * 32 + col;
        const float n2j = n2s[128 + lj];
#pragma unroll
        for (int h4 = 0; h4 < 4; ++h4) {
#pragma unroll
            for (int e = 0; e < 4; ++e) {
                const int li = wr * 32 + h4 * 8 + kh * 4 + e;
                const float c = acc[h4 * 4 + e];
                const float sq = fmaxf(n2s[li] + n2j - 2.0f * c, 0.0f);
                sC[li * CST + lj] = __expf(-__builtin_amdgcn_sqrtf(sq));
            }
        }
    }
    __syncthreads();

    // ---- reader: 16 lanes cover one row's 64 cols (256B contiguous S/St reads) ----
    float local = 0.0f;
    {
        const int rg = t >> 4;      // 0..31
        const int ln = t & 15;      // 0..15
        f32x4 s1a[4], s2a[4];
#pragma unroll
        for (int p = 0; p < 4; ++p) {
            const int li = p * 32 + rg;
            const int gi = ti * 128 + li;
            const int cb = tjc * 64 + ln * 4;
            s1a[p] = *reinterpret_cast<const f32x4*>(S + (size_t)gi * NS + cb);
            s2a[p] = single ? (f32x4)(0.0f)
                            : *reinterpret_cast<const f32x4*>(St + (size_t)gi * NS + cb);
        }
#pragma unroll
        for (int p = 0; p < 4; ++p) {
            const int li = p * 32 + rg;
            const int gi = ti * 128 + li;
            const f32x4 kdv = *reinterpret_cast<const f32x4*>(&sC[li * CST + ln * 4]);
#pragma unroll
            for (int e = 0; e < 4; ++e) {
                const int gj = tjc * 64 + ln * 4 + e;
                const float kd = kdv[e];
                const float s1 = s1a[p][e];
                if (single) {
                    float d = (gi == gj) ? (1.0f - s1) : (kd - s1);
                    d *= (s1 > 0.0f) ? 1.0f : 0.0f;
                    local += d * d;
                } else {
                    const float s2 = s2a[p][e];
                    const float d1 = (s1 > 0.0f) ? (kd - s1) : 0.0f;
                    const float d2 = (s2 > 0.0f) ? (kd - s2) : 0.0f;
                    local += d1 * d1 + d2 * d2;
                }
            }
        }
    }

#pragma unroll
    for (int off = 32; off >= 1; off >>= 1) local += __shfl_down(local, off, 64);
    if (lane == 0) red[wave] = local;
    __syncthreads();
    if (t == 0) {
        float s = 0.0f;
#pragma unroll
        for (int w = 0; w < 8; ++w) s += red[w];
        partial[(size_t)b * NTB + r20] = s;
    }
}

// =================== fallback path (R2, known-good; used if ws too small) ===================

__global__ __launch_bounds__(256) void norms_kernel(const float* __restrict__ dv,
                                                    float* __restrict__ n2) {
    const int row  = blockIdx.x * 4 + (threadIdx.x >> 6);
    const int lane = threadIdx.x & 63;
    const float4 v = *reinterpret_cast<const float4*>(dv + (size_t)row * DIM + lane * 4);
    float s = v.x * v.x + v.y * v.y + v.z * v.z + v.w * v.w;
#pragma unroll
    for (int off = 32; off >= 1; off >>= 1) s += __shfl_down(s, off, 64);
    if (lane == 0) n2[row] = s;
}

__global__ __launch_bounds__(256) void denom_kernel(const float* __restrict__ Smat,
                                                    float* __restrict__ dpartial) {
    const int t = threadIdx.x;
    const int lane = t & 63, wave = t >> 6;
    __shared__ float sred[4];
    float acc = 0.0f;
    const int base = blockIdx.x * 512;
#pragma unroll
    for (int r = 0; r < 2; ++r) {
        const int v4 = base + r * 256 + t;
        const float4 s4 = reinterpret_cast<const float4*>(Smat)[v4];
        const int idx0 = v4 * 4;
        const int i = idx0 >> 9;
#pragma unroll
        for (int c = 0; c < 4; ++c) {
            const float s = (&s4.x)[c];
            const int j = (idx0 + c) & (NS - 1);
            const float w = (s > 0.0f) ? 1.0f : 0.0f;
            const float e = (i == j) ? 1.0f : 0.0f;
            const float d = w - e;
            acc += d * d;
        }
    }
#pragma unroll
    for (int off = 32; off >= 1; off >>= 1) acc += __shfl_down(acc, off, 64);
    if (lane == 0) sred[wave] = acc;
    __syncthreads();
    if (t == 0) dpartial[blockIdx.x] = sred[0] + sred[1] + sred[2] + sred[3];
}

#define FLDSK 40
__global__ __launch_bounds__(256) void gram_f32_kernel(const float* __restrict__ dv,
                                                       const float* __restrict__ Smat,
                                                       const float* __restrict__ n2,
                                                       float* __restrict__ partial) {
    const int tile = blockIdx.x;
    const int b    = blockIdx.y;
    const int ti   = tile >> 2, tj = tile & 3;
    const int t    = threadIdx.x;
    const int wave = t >> 6, lane = t & 63;
    const int wr   = wave >> 1, wc = wave & 1;

    __shared__ bf16_t sA[128 * FLDSK];
    __shared__ bf16_t sB[128 * FLDSK];
    __shared__ float red[4];

    const float* Abase = dv + ((size_t)b * NS + (size_t)ti * 128) * DIM;
    const float* Bbase = dv + ((size_t)b * NS + (size_t)tj * 128) * DIM;

    f32x4 acc[4][4];
#pragma unroll
    for (int m = 0; m < 4; ++m)
#pragma unroll
        for (int n = 0; n < 4; ++n) acc[m][n] = (f32x4)(0.0f);

    const int fr = lane & 15;
    const int g  = lane >> 4;

    for (int ks = 0; ks < DIM; ks += 32) {
        float4 ra[4], rb[4];
#pragma unroll
        for (int i = 0; i < 4; ++i) {
            const int c   = i * 256 + t;
            const int row = c >> 3;
            const int kc  = (c & 7) * 4;
            ra[i] = *reinterpret_cast<const float4*>(Abase + (size_t)row * DIM + ks + kc);
            rb[i] = *reinterpret_cast<const float4*>(Bbase + (size_t)row * DIM + ks + kc);
        }
        __syncthreads();
#pragma unroll
        for (int i = 0; i < 4; ++i) {
            const int c   = i * 256 + t;
            const int row = c >> 3;
            const int kc  = (c & 7) * 4;
            bf16x4 va = { (bf16_t)ra[i].x, (bf16_t)ra[i].y, (bf16_t)ra[i].z, (bf16_t)ra[i].w };
            bf16x4 vb = { (bf16_t)rb[i].x, (bf16_t)rb[i].y, (bf16_t)rb[i].z, (bf16_t)rb[i].w };
            *reinterpret_cast<bf16x4*>(&sA[row * FLDSK + kc]) = va;
            *reinterpret_cast<bf16x4*>(&sB[row * FLDSK + kc]) = vb;
        }
        __syncthreads();

        bf16x8 afrag[4], bfrag[4];
#pragma unroll
        for (int m = 0; m < 4; ++m)
            afrag[m] = *reinterpret_cast<const bf16x8*>(&sA[(wr * 64 + m * 16 + fr) * FLDSK + g * 8]);
#pragma unroll
        for (int n = 0; n < 4; ++n)
            bfrag[n] = *reinterpret_cast<const bf16x8*>(&sB[(wc * 64 + n * 16 + fr) * FLDSK + g * 8]);
#pragma unroll
        for (int m = 0; m < 4; ++m)
#pragma unroll
            for (int n = 0; n < 4; ++n)
                acc[m][n] = __builtin_amdgcn_mfma_f32_16x16x32_bf16(afrag[m], bfrag[n], acc[m][n], 0, 0, 0);
    }

    float local = 0.0f;
    const float* n2b = n2 + (size_t)b * NS;
    const int rowbase = ti * 128 + wr * 64;
    const int colbase = tj * 128 + wc * 64;
#pragma unroll
    for (int m = 0; m < 4; ++m) {
#pragma unroll
        for (int n = 0; n < 4; ++n) {
            const int gi0 = rowbase + m * 16 + g * 4;
            const int gj  = colbase + n * 16 + fr;
            const float ncol = n2b[gj];
#pragma unroll
            for (int j = 0; j < 4; ++j) {
                const int gi = gi0 + j;
                const float cij = acc[m][n][j];
                float sq = fmaxf(n2b[gi] + ncol - 2.0f * cij, 0.0f);
                const float dist = sqrtf(sq);
                const float kd = __expf(-dist);
                const float s = Smat[(size_t)gi * NS + gj];
                const float w = (s > 0.0f) ? 1.0f : 0.0f;
                float d = (gi == gj) ? (1.0f - s) : (kd - s);
                d *= w;
                local += d * d;
            }
        }
    }
#pragma unroll
    for (int off = 32; off >= 1; off >>= 1) local += __shfl_down(local, off, 64);
    if (lane == 0) red[wave] = local;
    __syncthreads();
    if (t == 0) partial[(size_t)b * 16 + tile] = red[0] + red[1] + red[2] + red[3];
}

// =================== shared finalize ===================
__global__ __launch_bounds__(256) void finalize_kernel(const float* __restrict__ dpartial, int ndp,
                                                       const float* __restrict__ partial, int ntiles,
                                                       float* __restrict__ out) {
    const int t = threadIdx.x;
    const int lane = t & 63, wave = t >> 6;
    __shared__ float sred[4];
    __shared__ float sred2[4];

    float dacc = (t < ndp) ? dpartial[t] : 0.0f;
#pragma unroll
    for (int off = 32; off >= 1; off >>= 1) dacc += __shfl_down(dacc, off, 64);
    if (lane == 0) sred[wave] = dacc;
    __syncthreads();
    const float denom = sqrtf(sred[0] + sred[1] + sred[2] + sred[3]);

    float lsum = 0.0f;
    if (t < BATCH) {
        float ss = 0.0f;
        for (int k = 0; k < ntiles; ++k) ss += partial[(size_t)t * ntiles + k];
        lsum = 2.0f * sqrtf(ss) / denom;
    }
#pragma unroll
    for (int off = 32; off >= 1; off >>= 1) lsum += __shfl_down(lsum, off, 64);
    if (lane == 0) sred2[wave] = lsum;
    __syncthreads();
    if (t == 0) out[0] = sred2[0] + sred2[1] + sred2[2] + sred2[3];
}

extern "C" void kernel_launch(void* const* d_in, const int* in_sizes, int n_in,
                              void* d_out, int out_size, void* d_ws, size_t ws_size,
                              hipStream_t stream) {
    const float* dv   = (const float*)d_in[0];   // [128,512,256] fp32
    const float* Smat = (const float*)d_in[1];   // [512,512] fp32
    float* out = (float*)d_out;

    const size_t f8_bytes = (size_t)BATCH * NS * DIM;     // 16 MB
    const size_t st_bytes = (size_t)NS * NS * 4;          // 1 MB
    const size_t n2_bytes = (size_t)BATCH * NS * 4;       // 256 KB
    const size_t pt_bytes = (size_t)BATCH * NTB * 4;      // 10 KB
    const size_t dp_bytes = 256 * 4;
    const size_t need = f8_bytes + st_bytes + n2_bytes + pt_bytes + dp_bytes;

    if (ws_size >= need) {
        char* w = (char*)d_ws;
        unsigned char* f8 = (unsigned char*)w;  w += f8_bytes;
        float* St      = (float*)w;   w += st_bytes;
        float* n2g     = (float*)w;   w += n2_bytes;
        float* partial = (float*)w;   w += pt_bytes;
        float* dpart   = (float*)w;

        prep_st_kernel<<<dim3(2304), 256, 0, stream>>>(dv, Smat, f8, n2g, St, dpart);
        gram_pair_kernel<<<dim3(NTB * BATCH), 512, 0, stream>>>(f8, n2g, Smat, St, partial);
        finalize_kernel<<<dim3(1), 256, 0, stream>>>(dpart, 256, partial, NTB, out);
    } else {
        float* n2      = (float*)d_ws;
        float* partial = n2 + (size_t)BATCH * NS;
        float* dpart   = partial + (size_t)BATCH * 16;

        norms_kernel<<<dim3(BATCH * NS / 4), 256, 0, stream>>>(dv, n2);
        denom_kernel<<<dim3(128), 256, 0, stream>>>(Smat, dpart);
        gram_f32_kernel<<<dim3(16, BATCH), 256, 0, stream>>>(dv, Smat, n2, partial);
        finalize_kernel<<<dim3(1), 256, 0, stream>>>(dpart, 128, partial, 16, out);
    }
}